// Round 10
// baseline (466.617 us; speedup 1.0000x reference)
//
#include <hip/hip_runtime.h>
#include <stdint.h>

#define D 128
#define CHUNK 3200

typedef __attribute__((ext_vector_type(8))) __bf16 bf16x8;
typedef __attribute__((ext_vector_type(4))) __bf16 bf16x4;
typedef __attribute__((ext_vector_type(4))) float f32x4;

// ---------------------------------------------------------------------------
// edge_index dtype detection (int64 per reference vs int32 from x64-disabled JAX)
__global__ void detect_idx(const void* ei, int* flag, int n_nodes) {
    if (blockIdx.x == 0 && threadIdx.x == 0) {
        const long long* p = (const long long*)ei;
        int is64 = 1;
        for (int i = 0; i < 64; ++i) {
            long long v = p[i];
            if (v < 0 || v >= (long long)n_nodes) { is64 = 0; break; }
        }
        *flag = is64;
    }
}

__global__ void convert_idx(const void* ei, const int* flag,
                            int* src32, int* dst32, int nE) {
    int e = blockIdx.x * blockDim.x + threadIdx.x;
    if (e >= nE) return;
    if (*flag) {
        const long long* p = (const long long*)ei;
        src32[e] = (int)p[e];
        dst32[e] = (int)p[(size_t)nE + e];
    } else {
        const int* p = (const int*)ei;
        src32[e] = p[e];
        dst32[e] = p[nE + e];
    }
}

// ---------------------------------------------------------------------------
// Bucketed CSR build (R8-verified). Bucket g = dst>>9; final scatter per
// bucket done by ONE workgroup -> no cross-XCD line bouncing / write amp.
__global__ __launch_bounds__(256) void bucket_hist(
        const int* __restrict__ dst32, int* __restrict__ bcnt, int nE) {
    __shared__ int l[256];
    l[threadIdx.x] = 0;
    __syncthreads();
    int stride = gridDim.x * 256;
    for (int e = blockIdx.x * 256 + threadIdx.x; e < nE; e += stride)
        atomicAdd(&l[dst32[e] >> 9], 1);
    __syncthreads();
    int v = l[threadIdx.x];
    if (v) atomicAdd(&bcnt[threadIdx.x], v);
}

__global__ void bucket_scan(const int* __restrict__ bcnt, int* __restrict__ bstart,
                            int* __restrict__ bcur, int G, int nE,
                            int* __restrict__ offsets, int n) {
    __shared__ int s[256];
    int t = threadIdx.x;
    int v = (t < G) ? bcnt[t] : 0;
    s[t] = v;
    __syncthreads();
    for (int off = 1; off < 256; off <<= 1) {
        int u = 0;
        if (t >= off) u = s[t - off];
        __syncthreads();
        if (t >= off) s[t] += u;
        __syncthreads();
    }
    if (t < G) { int ex = s[t] - v; bstart[t] = ex; bcur[t] = ex; }
    if (t == 0) offsets[n] = nE;
}

__global__ __launch_bounds__(256) void bucket_fill(
        const int* __restrict__ src32, const int* __restrict__ dst32,
        int* __restrict__ bcur, int* __restrict__ ebs, int* __restrict__ ebd,
        int nE) {
    __shared__ int ls[CHUNK], ld_[CHUNK];
    __shared__ int lcnt[256], lbase[256], lcur[256];
    int e0 = blockIdx.x * CHUNK;
    int cnt = nE - e0;
    if (cnt > CHUNK) cnt = CHUNK;
    if (cnt < 0) cnt = 0;
    for (int i = threadIdx.x; i < cnt; i += 256) {
        ls[i]  = src32[e0 + i];
        ld_[i] = dst32[e0 + i];
    }
    lcnt[threadIdx.x] = 0;
    __syncthreads();
    for (int i = threadIdx.x; i < cnt; i += 256)
        atomicAdd(&lcnt[ld_[i] >> 9], 1);
    __syncthreads();
    int c = lcnt[threadIdx.x];
    if (c > 0) lbase[threadIdx.x] = atomicAdd(&bcur[threadIdx.x], c);
    lcur[threadIdx.x] = 0;
    __syncthreads();
    for (int i = threadIdx.x; i < cnt; i += 256) {
        int g = ld_[i] >> 9;
        int p = lbase[g] + atomicAdd(&lcur[g], 1);
        ebs[p] = ls[i];
        ebd[p] = ld_[i];
    }
}

__global__ __launch_bounds__(256) void bucket_scatter(
        const int* __restrict__ ebs, const int* __restrict__ ebd,
        const int* __restrict__ bstart, const int* __restrict__ bcnt,
        int* __restrict__ offsets, int* __restrict__ csr, int n) {
    __shared__ int ncnt[512], nofs[512], ps[256];
    int g = blockIdx.x;
    int base = bstart[g];
    int cnt = bcnt[g];
    int n0 = g << 9;
    int nr = n - n0; if (nr > 512) nr = 512;
    for (int i = threadIdx.x; i < 512; i += 256) ncnt[i] = 0;
    __syncthreads();
    for (int i = threadIdx.x; i < cnt; i += 256)
        atomicAdd(&ncnt[ebd[base + i] - n0], 1);
    __syncthreads();
    int t = threadIdx.x;
    int c0 = ncnt[2 * t], c1 = ncnt[2 * t + 1];
    ps[t] = c0 + c1;
    __syncthreads();
    for (int off = 1; off < 256; off <<= 1) {
        int u = 0;
        if (t >= off) u = ps[t - off];
        __syncthreads();
        if (t >= off) ps[t] += u;
        __syncthreads();
    }
    int pex = ps[t] - (c0 + c1);
    nofs[2 * t] = pex;
    nofs[2 * t + 1] = pex + c0;
    __syncthreads();
    for (int i = threadIdx.x; i < nr; i += 256)
        offsets[n0 + i] = base + nofs[i];
    for (int i = threadIdx.x; i < 512; i += 256) ncnt[i] = 0;   // reuse as cursor
    __syncthreads();
    for (int i = threadIdx.x; i < cnt; i += 256) {
        int d = ebd[base + i] - n0;
        int p = base + nofs[d] + atomicAdd(&ncnt[d], 1);
        csr[p] = ebs[base + i];
    }
}

// ---------------------------------------------------------------------------
// W preprocessing: stacked [Wl;Wr] transposed to [col][k], split bf16 hi/lo.
__global__ void build_wt(const float* __restrict__ Wa, const float* __restrict__ Wr,
                         __bf16* __restrict__ WtHi, __bf16* __restrict__ WtLo) {
    int idx = blockIdx.x * 256 + threadIdx.x;         // 3*128*256 total
    if (idx >= 3 * 128 * 256) return;
    int L = idx / (128 * 256);
    int rem = idx % (128 * 256);
    int c = rem / 256;
    int k = rem % 256;
    float v = (k < 128) ? Wa[((size_t)L * 128 + k) * 128 + c]
                        : Wr[((size_t)L * 128 + (k - 128)) * 128 + c];
    __bf16 h = (__bf16)v;
    __bf16 l = (__bf16)(v - (float)h);
    WtHi[idx] = h;
    WtLo[idx] = l;
}

// ---------------------------------------------------------------------------
// x fp32 -> bf16 single plane (once, layer-0 input)
__global__ void cvt_x(const float* __restrict__ x, __bf16* __restrict__ a,
                      int total8) {
    int i = blockIdx.x * 256 + threadIdx.x;           // 8 floats per thread
    if (i >= total8) return;
    const float4* p = (const float4*)(x + (size_t)i * 8);
    float4 v0 = p[0], v1 = p[1];
    float vv[8] = {v0.x, v0.y, v0.z, v0.w, v1.x, v1.y, v1.z, v1.w};
    bf16x8 h;
    #pragma unroll
    for (int j = 0; j < 8; ++j) h[j] = (__bf16)vv[j];
    *(bf16x8*)(a + (size_t)i * 8) = h;
}

// ---------------------------------------------------------------------------
// FUSED layer: per 16-row tile, gather+mean the tile's neighbors (CSR segment
// is contiguous) directly into the swizzled sA LDS tile, then the verified
// gemm7 MFMA + epilogue. Removes the meanP round-trip and overlaps gather
// with MFMA across the 2 co-resident blocks/CU.
// 512 thr = 8 waves. Gather: 32 x 16-lane groups; groups g and g+16 split row
// (g&15)'s neighbor list in half; partials combined via LDS (sU). Root act
// row staged by groups 16..31 into sA chunks 16..31. MFMA: wave w owns cols
// w*16..+15, W hi/lo frags VGPR-resident, swizzled ds_reads (byte ^=
// (row&7)<<4 on 16B chunks), mfma(W,A): out_row = r16, out_col = kg*4+j.
__global__ __launch_bounds__(512, 4) void sage_fused(
        const __bf16* __restrict__ act, const int* __restrict__ csr,
        const int* __restrict__ offs,
        const __bf16* __restrict__ WtHi, const __bf16* __restrict__ WtLo,
        const float* __restrict__ bias,
        __bf16* __restrict__ oB, float* __restrict__ oF,
        int n, int mode, int ntiles) {
    __shared__ __align__(16) char sA[8192];   // [row:512B][32 x 16B chunks, swz]
    __shared__ __align__(16) char sU[8192];   // union: f32 partials [16][16][8] / sC
    int tid  = threadIdx.x;
    int wave = tid >> 6;
    int lane = tid & 63;
    int r16  = lane & 15;
    int kg   = lane >> 4;
    int colbase = wave * 16;

    // W fragments: this wave's 16 cols, full stacked K, hi+lo (64 VGPR)
    bf16x8 BH[8], BL[8];
    #pragma unroll
    for (int c8 = 0; c8 < 8; ++c8) {
        size_t o = (size_t)(colbase + r16) * 256 + c8 * 32 + kg * 8;
        BH[c8] = *(const bf16x8*)(WtHi + o);
        BL[c8] = *(const bf16x8*)(WtLo + o);
    }
    float4 bv = *(const float4*)(bias + colbase + kg * 4);

    // swizzled ds_read offsets for MFMA A-fragments
    int xm = (r16 & 7) << 4;
    int kb[8];
    #pragma unroll
    for (int c8 = 0; c8 < 8; ++c8)
        kb[c8] = r16 * 512 + ((c8 * 64 + kg * 16) ^ xm);

    // gather-group geometry
    int g    = tid >> 4;        // 0..31
    int l16  = tid & 15;
    int lrow = g & 15;          // row within tile
    bool hiH = g >= 16;

    for (int t = blockIdx.x; t < ntiles; t += gridDim.x) {
        int r = t * 16 + lrow;

        // ---- phase 1a: gather this group's half of row r's neighbor list
        float a0=0.f,a1=0.f,a2=0.f,a3=0.f,a4=0.f,a5=0.f,a6=0.f,a7=0.f;
        int beg = 0, end = 0;
        if (r < n) { beg = offs[r]; end = offs[r + 1]; }
        int deg = end - beg;
        int mid = beg + ((deg + 1) >> 1);
        int lo = hiH ? mid : beg;
        int hi = hiH ? end : mid;
        int i = lo;
        for (; i + 8 <= hi; i += 8) {
            bf16x8 v[8];
            #pragma unroll
            for (int u = 0; u < 8; ++u)
                v[u] = *(const bf16x8*)(act + (size_t)csr[i + u] * D + l16 * 8);
            #pragma unroll
            for (int u = 0; u < 8; ++u) {
                a0 += (float)v[u][0]; a1 += (float)v[u][1];
                a2 += (float)v[u][2]; a3 += (float)v[u][3];
                a4 += (float)v[u][4]; a5 += (float)v[u][5];
                a6 += (float)v[u][6]; a7 += (float)v[u][7];
            }
        }
        for (; i < hi; ++i) {
            bf16x8 v = *(const bf16x8*)(act + (size_t)csr[i] * D + l16 * 8);
            a0 += (float)v[0]; a1 += (float)v[1];
            a2 += (float)v[2]; a3 += (float)v[3];
            a4 += (float)v[4]; a5 += (float)v[5];
            a6 += (float)v[6]; a7 += (float)v[7];
        }

        if (hiH) {
            float* sp = (float*)sU + ((lrow << 4) + l16) * 8;
            sp[0]=a0; sp[1]=a1; sp[2]=a2; sp[3]=a3;
            sp[4]=a4; sp[5]=a5; sp[6]=a6; sp[7]=a7;
            // stage root act row chunk (sA chunks 16..31)
            int4 av = make_int4(0, 0, 0, 0);
            if (r < n) av = *(const int4*)(act + (size_t)r * D + l16 * 8);
            *(int4*)(sA + lrow * 512 + ((((16 + l16) * 16)) ^ ((lrow & 7) << 4))) = av;
        }
        __syncthreads();   // S1: partials + act-half staged

        if (!hiH) {
            const float* sp = (const float*)sU + ((lrow << 4) + l16) * 8;
            float inv = 1.0f / (float)(deg > 1 ? deg : 1);
            bf16x8 m;
            m[0] = (__bf16)((a0 + sp[0]) * inv);
            m[1] = (__bf16)((a1 + sp[1]) * inv);
            m[2] = (__bf16)((a2 + sp[2]) * inv);
            m[3] = (__bf16)((a3 + sp[3]) * inv);
            m[4] = (__bf16)((a4 + sp[4]) * inv);
            m[5] = (__bf16)((a5 + sp[5]) * inv);
            m[6] = (__bf16)((a6 + sp[6]) * inv);
            m[7] = (__bf16)((a7 + sp[7]) * inv);
            *(bf16x8*)(sA + lrow * 512 + ((l16 * 16) ^ ((lrow & 7) << 4))) = m;
        }
        __syncthreads();   // S2: sA complete

        // ---- phase 2: MFMA (verbatim gemm7)
        f32x4 acc = (f32x4){0.f, 0.f, 0.f, 0.f};
        #pragma unroll
        for (int c8 = 0; c8 < 8; ++c8) {
            bf16x8 a = *(const bf16x8*)(sA + kb[c8]);
            acc = __builtin_amdgcn_mfma_f32_16x16x32_bf16(BH[c8], a, acc, 0, 0, 0);
            acc = __builtin_amdgcn_mfma_f32_16x16x32_bf16(BL[c8], a, acc, 0, 0, 0);
        }

        // ---- epilogue: acc -> sU(sC) (row = r16, col = colbase + kg*4 + j)
        float v0 = acc[0] + bv.x;
        float v1 = acc[1] + bv.y;
        float v2 = acc[2] + bv.z;
        float v3 = acc[3] + bv.w;
        if (mode == 0) {
            v0 = fmaxf(v0, 0.f); v1 = fmaxf(v1, 0.f);
            v2 = fmaxf(v2, 0.f); v3 = fmaxf(v3, 0.f);
            bf16x4 h4;
            h4[0] = (__bf16)v0; h4[1] = (__bf16)v1;
            h4[2] = (__bf16)v2; h4[3] = (__bf16)v3;
            *(bf16x4*)(sU + r16 * 256 + (colbase + kg * 4) * 2) = h4;
        } else {
            *(f32x4*)(sU + r16 * 512 + (colbase + kg * 4) * 4) =
                (f32x4){v0, v1, v2, v3};
        }
        __syncthreads();   // S3: sC complete (MFMA reads of sA also done)

        // ---- cooperative coalesced store of the 16x128 tile
        if (mode == 0) {
            if (tid < 256) {
                int rr = tid >> 4, c16 = tid & 15;
                int grow = t * 16 + rr;
                if (grow < n) {
                    int4 h = *(const int4*)(sU + rr * 256 + c16 * 16);
                    *(int4*)(oB + (size_t)grow * D + c16 * 8) = h;
                }
            }
        } else {
            int rr = tid >> 5, c = tid & 31;
            int grow = t * 16 + rr;
            if (grow < n) {
                f32x4 f = *(const f32x4*)(sU + rr * 512 + c * 16);
                *(f32x4*)(oF + (size_t)grow * D + c * 4) = f;
            }
        }
        __syncthreads();   // S4: sU/sA free for next tile
    }
}

// ---------------------------------------------------------------------------
extern "C" void kernel_launch(void* const* d_in, const int* in_sizes, int n_in,
                              void* d_out, int out_size, void* d_ws, size_t ws_size,
                              hipStream_t stream) {
    const float* x  = (const float*)d_in[0];
    const void*  ei = d_in[1];
    const float* Wa = (const float*)d_in[2];   // [3,128,128]
    const float* Wr = (const float*)d_in[3];   // [3,128,128]
    const float* bb = (const float*)d_in[4];   // [3,128]
    float* outp = (float*)d_out;

    int n  = in_sizes[0] / D;          // 100000
    int nE = in_sizes[1] / 2;          // 1600000
    int G  = (n + 511) >> 9;           // 512-node buckets

    char* ws = (char*)d_ws;
    size_t off = 0;
    auto alloc = [&](size_t bytes) -> char* {
        char* p = ws + off;
        off = (off + bytes + 255) & ~(size_t)255;
        return p;
    };
    int* flag      = (int*)alloc(4);
    int* src32     = (int*)alloc((size_t)nE * 4);
    int* dst32     = (int*)alloc((size_t)nE * 4);
    int* offsets   = (int*)alloc(((size_t)n + 1) * 4);
    int* csr_src   = (int*)alloc((size_t)nE * 4);
    int* ebs       = (int*)alloc((size_t)nE * 4);
    int* ebd       = (int*)alloc((size_t)nE * 4);
    int* bcnt      = (int*)alloc(1024);
    int* bstart    = (int*)alloc(1024);
    int* bcur      = (int*)alloc(1024);
    __bf16* actA   = (__bf16*)alloc((size_t)n * D * 2);
    __bf16* actB   = (__bf16*)alloc((size_t)n * D * 2);
    __bf16* WtHi   = (__bf16*)alloc((size_t)3 * 128 * 256 * 2);
    __bf16* WtLo   = (__bf16*)alloc((size_t)3 * 128 * 256 * 2);
    (void)ws_size; (void)n_in; (void)out_size;

    const int B = 256;
    int ge = (nE + B - 1) / B;

    // 1) index probe + conversion + W transpose/split + x convert
    hipLaunchKernelGGL(detect_idx, dim3(1), dim3(64), 0, stream, ei, flag, n);
    hipLaunchKernelGGL(convert_idx, dim3(ge), dim3(B), 0, stream,
                       ei, flag, src32, dst32, nE);
    hipLaunchKernelGGL(build_wt, dim3(384), dim3(256), 0, stream, Wa, Wr, WtHi, WtLo);
    int total8 = n * D / 8;
    hipLaunchKernelGGL(cvt_x, dim3((total8 + 255) / 256), dim3(256), 0, stream,
                       x, actA, total8);

    // 2) bucketed CSR build
    hipMemsetAsync(bcnt, 0, 1024, stream);
    hipLaunchKernelGGL(bucket_hist, dim3(512), dim3(B), 0, stream, dst32, bcnt, nE);
    hipLaunchKernelGGL(bucket_scan, dim3(1), dim3(B), 0, stream,
                       bcnt, bstart, bcur, G, nE, offsets, n);
    hipLaunchKernelGGL(bucket_fill, dim3((nE + CHUNK - 1) / CHUNK), dim3(B), 0, stream,
                       src32, dst32, bcur, ebs, ebd, nE);
    hipLaunchKernelGGL(bucket_scatter, dim3(G), dim3(B), 0, stream,
                       ebs, ebd, bstart, bcnt, offsets, csr_src, n);

    // 3) fused layers (ping-pong actA <-> actB)
    int ntiles = (n + 15) / 16;
    int grid = 512;                    // 2 blocks/CU at 512 threads
    const int WSTRIDE = 128 * 256;

    // layer 0: actA -> actB (ReLU, bf16)
    hipLaunchKernelGGL(sage_fused, dim3(grid), dim3(512), 0, stream,
                       actA, csr_src, offsets, WtHi + 0 * WSTRIDE, WtLo + 0 * WSTRIDE,
                       bb + 0 * D, actB, outp, n, 0, ntiles);

    // layer 1: actB -> actA (ReLU, bf16)
    hipLaunchKernelGGL(sage_fused, dim3(grid), dim3(512), 0, stream,
                       actB, csr_src, offsets, WtHi + 1 * WSTRIDE, WtLo + 1 * WSTRIDE,
                       bb + 1 * D, actA, outp, n, 0, ntiles);

    // layer 2: actA -> d_out (no ReLU, fp32)
    hipLaunchKernelGGL(sage_fused, dim3(grid), dim3(512), 0, stream,
                       actA, csr_src, offsets, WtHi + 2 * WSTRIDE, WtLo + 2 * WSTRIDE,
                       bb + 2 * D, actB, outp, n, 1, ntiles);
}

// Round 11
// 343.868 us; speedup vs baseline: 1.3570x; 1.3570x over previous
//
#include <hip/hip_runtime.h>
#include <stdint.h>

#define D 128
#define CHUNK 6400

typedef __attribute__((ext_vector_type(8))) __bf16 bf16x8;
typedef __attribute__((ext_vector_type(4))) __bf16 bf16x4;
typedef __attribute__((ext_vector_type(4))) float f32x4;

// ---------------------------------------------------------------------------
// edge_index dtype detection (int64 per reference vs int32 from x64-disabled JAX)
__global__ void detect_idx(const void* ei, int* flag, int n_nodes) {
    if (blockIdx.x == 0 && threadIdx.x == 0) {
        const long long* p = (const long long*)ei;
        int is64 = 1;
        for (int i = 0; i < 64; ++i) {
            long long v = p[i];
            if (v < 0 || v >= (long long)n_nodes) { is64 = 0; break; }
        }
        *flag = is64;
    }
}

// ---------------------------------------------------------------------------
// one pass over edge_index: emit packed edge word (src<<9 | dst&511), bucket
// byte (dst>>9, <256 for n<=131072), and the bucket histogram (LDS -> global).
__global__ __launch_bounds__(256) void convert_pack(
        const void* __restrict__ ei, const int* __restrict__ flag,
        unsigned int* __restrict__ eword, unsigned char* __restrict__ gb,
        int* __restrict__ bcnt, int nE) {
    __shared__ int l[256];
    l[threadIdx.x] = 0;
    __syncthreads();
    bool is64 = *flag != 0;
    int stride = gridDim.x * 256;
    for (int e = blockIdx.x * 256 + threadIdx.x; e < nE; e += stride) {
        int s, d;
        if (is64) {
            const long long* p = (const long long*)ei;
            s = (int)p[e];
            d = (int)p[(size_t)nE + e];
        } else {
            const int* p = (const int*)ei;
            s = p[e];
            d = p[nE + e];
        }
        eword[e] = ((unsigned)s << 9) | (unsigned)(d & 511);
        gb[e] = (unsigned char)(d >> 9);
        atomicAdd(&l[d >> 9], 1);
    }
    __syncthreads();
    int v = l[threadIdx.x];
    if (v) atomicAdd(&bcnt[threadIdx.x], v);
}

// exclusive scan of bucket counts -> bstart, bcur; offsets[n]=nE
__global__ void bucket_scan(const int* __restrict__ bcnt, int* __restrict__ bstart,
                            int* __restrict__ bcur, int G, int nE,
                            int* __restrict__ offsets, int n) {
    __shared__ int s[256];
    int t = threadIdx.x;
    int v = (t < G) ? bcnt[t] : 0;
    s[t] = v;
    __syncthreads();
    for (int off = 1; off < 256; off <<= 1) {
        int u = 0;
        if (t >= off) u = s[t - off];
        __syncthreads();
        if (t >= off) s[t] += u;
        __syncthreads();
    }
    if (t < G) { int ex = s[t] - v; bstart[t] = ex; bcur[t] = ex; }
    if (t == 0) offsets[n] = nE;
}

// pass 1: chunk -> LDS, per-bucket count, reserve, write packed words
// bucket-major. Per-(block,bucket) runs contiguous -> no cross-XCD line mix.
__global__ __launch_bounds__(256) void bucket_fill2(
        const unsigned int* __restrict__ eword, const unsigned char* __restrict__ gb,
        int* __restrict__ bcur, unsigned int* __restrict__ ebuf, int nE) {
    __shared__ unsigned int lw[CHUNK];
    __shared__ unsigned char lg[CHUNK];
    __shared__ int lcnt[256], lbase[256], lcur[256];
    int e0 = blockIdx.x * CHUNK;
    int cnt = nE - e0;
    if (cnt > CHUNK) cnt = CHUNK;
    if (cnt < 0) cnt = 0;
    for (int i = threadIdx.x; i < cnt; i += 256) {
        lw[i] = eword[e0 + i];
        lg[i] = gb[e0 + i];
    }
    lcnt[threadIdx.x] = 0;
    __syncthreads();
    for (int i = threadIdx.x; i < cnt; i += 256)
        atomicAdd(&lcnt[lg[i]], 1);
    __syncthreads();
    int c = lcnt[threadIdx.x];
    if (c > 0) lbase[threadIdx.x] = atomicAdd(&bcur[threadIdx.x], c);
    lcur[threadIdx.x] = 0;
    __syncthreads();
    for (int i = threadIdx.x; i < cnt; i += 256) {
        int g = lg[i];
        int p = lbase[g] + atomicAdd(&lcur[g], 1);
        ebuf[p] = lw[i];
    }
}

// pass 2: one block per bucket; node-hist, scan, offsets slice, local scatter.
__global__ __launch_bounds__(256) void bucket_scatter2(
        const unsigned int* __restrict__ ebuf,
        const int* __restrict__ bstart, const int* __restrict__ bcnt,
        int* __restrict__ offsets, int* __restrict__ csr, int n) {
    __shared__ int ncnt[512], nofs[512], ps[256];
    int g = blockIdx.x;
    int base = bstart[g];
    int cnt = bcnt[g];
    int n0 = g << 9;
    int nr = n - n0; if (nr > 512) nr = 512;
    for (int i = threadIdx.x; i < 512; i += 256) ncnt[i] = 0;
    __syncthreads();
    for (int i = threadIdx.x; i < cnt; i += 256)
        atomicAdd(&ncnt[ebuf[base + i] & 511], 1);
    __syncthreads();
    int t = threadIdx.x;
    int c0 = ncnt[2 * t], c1 = ncnt[2 * t + 1];
    ps[t] = c0 + c1;
    __syncthreads();
    for (int off = 1; off < 256; off <<= 1) {
        int u = 0;
        if (t >= off) u = ps[t - off];
        __syncthreads();
        if (t >= off) ps[t] += u;
        __syncthreads();
    }
    int pex = ps[t] - (c0 + c1);
    nofs[2 * t] = pex;
    nofs[2 * t + 1] = pex + c0;
    __syncthreads();
    for (int i = threadIdx.x; i < nr; i += 256)
        offsets[n0 + i] = base + nofs[i];
    for (int i = threadIdx.x; i < 512; i += 256) ncnt[i] = 0;   // reuse as cursor
    __syncthreads();
    for (int i = threadIdx.x; i < cnt; i += 256) {
        unsigned int w = ebuf[base + i];
        int d = w & 511;
        int p = base + nofs[d] + atomicAdd(&ncnt[d], 1);
        csr[p] = (int)(w >> 9);
    }
}

// ---------------------------------------------------------------------------
// W preprocessing: stacked [Wl;Wr] transposed to [col][k], split bf16 hi/lo.
__global__ void build_wt(const float* __restrict__ Wa, const float* __restrict__ Wr,
                         __bf16* __restrict__ WtHi, __bf16* __restrict__ WtLo) {
    int idx = blockIdx.x * 256 + threadIdx.x;         // 3*128*256 total
    if (idx >= 3 * 128 * 256) return;
    int L = idx / (128 * 256);
    int rem = idx % (128 * 256);
    int c = rem / 256;
    int k = rem % 256;
    float v = (k < 128) ? Wa[((size_t)L * 128 + k) * 128 + c]
                        : Wr[((size_t)L * 128 + (k - 128)) * 128 + c];
    __bf16 h = (__bf16)v;
    __bf16 l = (__bf16)(v - (float)h);
    WtHi[idx] = h;
    WtLo[idx] = l;
}

// ---------------------------------------------------------------------------
// x fp32 -> bf16 single plane (once, layer-0 input)
__global__ void cvt_x(const float* __restrict__ x, __bf16* __restrict__ a,
                      int total8) {
    int i = blockIdx.x * 256 + threadIdx.x;           // 8 floats per thread
    if (i >= total8) return;
    const float4* p = (const float4*)(x + (size_t)i * 8);
    float4 v0 = p[0], v1 = p[1];
    float vv[8] = {v0.x, v0.y, v0.z, v0.w, v1.x, v1.y, v1.z, v1.w};
    bf16x8 h;
    #pragma unroll
    for (int j = 0; j < 8; ++j) h[j] = (__bf16)vv[j];
    *(bf16x8*)(a + (size_t)i * 8) = h;
}

// ---------------------------------------------------------------------------
// mean aggregation (R8/R9-proven): gather bf16 plane, one node per 16-lane
// group, 8x unrolled row gathers, fp32 accumulate.
__global__ __launch_bounds__(256) void agg_mean5(
        const __bf16* __restrict__ act, const int* __restrict__ csr,
        const int* __restrict__ offs, __bf16* __restrict__ mean, int n) {
    int node = (blockIdx.x * blockDim.x + threadIdx.x) >> 4;
    int l8 = (threadIdx.x & 15) << 3;
    if (node >= n) return;
    int beg = offs[node], end = offs[node + 1];
    float acc[8] = {0.f, 0.f, 0.f, 0.f, 0.f, 0.f, 0.f, 0.f};
    int i = beg;
    for (; i + 8 <= end; i += 8) {
        bf16x8 v[8];
        #pragma unroll
        for (int u = 0; u < 8; ++u)
            v[u] = *(const bf16x8*)(act + (size_t)csr[i + u] * D + l8);
        #pragma unroll
        for (int u = 0; u < 8; ++u)
            #pragma unroll
            for (int j = 0; j < 8; ++j) acc[j] += (float)v[u][j];
    }
    for (; i + 4 <= end; i += 4) {
        bf16x8 v[4];
        #pragma unroll
        for (int u = 0; u < 4; ++u)
            v[u] = *(const bf16x8*)(act + (size_t)csr[i + u] * D + l8);
        #pragma unroll
        for (int u = 0; u < 4; ++u)
            #pragma unroll
            for (int j = 0; j < 8; ++j) acc[j] += (float)v[u][j];
    }
    for (; i < end; ++i) {
        bf16x8 v = *(const bf16x8*)(act + (size_t)csr[i] * D + l8);
        #pragma unroll
        for (int j = 0; j < 8; ++j) acc[j] += (float)v[j];
    }
    int deg = end - beg;
    float inv = 1.0f / (float)(deg > 1 ? deg : 1);
    bf16x8 h;
    #pragma unroll
    for (int j = 0; j < 8; ++j) h[j] = (__bf16)(acc[j] * inv);
    *(bf16x8*)(mean + (size_t)node * D + l8) = h;
}

// ---------------------------------------------------------------------------
// MFMA GEMM v7 (R9-proven): 512-thr block = 8 waves; one 16-row tile x all
// 128 cols; A-tile staged once into swizzled LDS (byte ^= (row&7)<<4),
// double-buffered; W hi/lo frags VGPR-resident; mfma(W,A): out_row = r16,
// out_col = colbase + kg*4 + j; sC-transpose coalesced epilogue.
__global__ __launch_bounds__(512, 4) void sage_gemm7(
        const __bf16* __restrict__ mean, const __bf16* __restrict__ act,
        const __bf16* __restrict__ WtHi, const __bf16* __restrict__ WtLo,
        const float* __restrict__ bias,
        __bf16* __restrict__ oB, float* __restrict__ oF,
        int n, int mode, int ntiles) {
    __shared__ __align__(16) char sA[2][8192];   // [buf][row:512B][k swz]
    __shared__ __align__(16) char sC[8192];      // epilogue transpose tile
    int tid  = threadIdx.x;
    int wave = tid >> 6;
    int lane = tid & 63;
    int r16  = lane & 15;
    int kg   = lane >> 4;
    int colbase = wave * 16;

    bf16x8 BH[8], BL[8];
    #pragma unroll
    for (int c8 = 0; c8 < 8; ++c8) {
        size_t o = (size_t)(colbase + r16) * 256 + c8 * 32 + kg * 8;
        BH[c8] = *(const bf16x8*)(WtHi + o);
        BL[c8] = *(const bf16x8*)(WtLo + o);
    }
    float4 bv = *(const float4*)(bias + colbase + kg * 4);

    int xm = (r16 & 7) << 4;
    int kb[8];
    #pragma unroll
    for (int c8 = 0; c8 < 8; ++c8)
        kb[c8] = r16 * 512 + ((c8 * 64 + kg * 16) ^ xm);

    int srow = tid >> 5;           // 0..15
    int sc16 = tid & 31;           // 0..31 (32 x 16B per row)
    int sdst = srow * 512 + ((sc16 * 16) ^ ((srow & 7) << 4));

    auto stage_load = [&](int t, int4& r) {
        int grow = t * 16 + srow;
        if (grow < n) {
            const __bf16* src = (sc16 < 16)
                ? (mean + (size_t)grow * D + sc16 * 8)
                : (act  + (size_t)grow * D + (sc16 - 16) * 8);
            r = *(const int4*)src;
        } else {
            r = make_int4(0, 0, 0, 0);
        }
    };

    int tstride = gridDim.x;
    int t = blockIdx.x;

    int4 sreg = make_int4(0, 0, 0, 0);
    if (t < ntiles) stage_load(t, sreg);
    *(int4*)(sA[0] + sdst) = sreg;
    __syncthreads();
    int cur = 0;

    for (; t < ntiles; t += tstride) {
        int tn = t + tstride;
        bool hasnext = tn < ntiles;
        int4 nreg;
        if (hasnext) stage_load(tn, nreg);

        f32x4 acc = (f32x4){0.f, 0.f, 0.f, 0.f};
        const char* base = sA[cur];
        #pragma unroll
        for (int c8 = 0; c8 < 8; ++c8) {
            bf16x8 a = *(const bf16x8*)(base + kb[c8]);
            acc = __builtin_amdgcn_mfma_f32_16x16x32_bf16(BH[c8], a, acc, 0, 0, 0);
            acc = __builtin_amdgcn_mfma_f32_16x16x32_bf16(BL[c8], a, acc, 0, 0, 0);
        }

        __syncthreads();                       // buf[cur] reads + prev sC reads done
        if (hasnext) *(int4*)(sA[cur ^ 1] + sdst) = nreg;

        float v0 = acc[0] + bv.x;
        float v1 = acc[1] + bv.y;
        float v2 = acc[2] + bv.z;
        float v3 = acc[3] + bv.w;
        if (mode == 0) {
            v0 = fmaxf(v0, 0.f); v1 = fmaxf(v1, 0.f);
            v2 = fmaxf(v2, 0.f); v3 = fmaxf(v3, 0.f);
            bf16x4 h4;
            h4[0] = (__bf16)v0; h4[1] = (__bf16)v1;
            h4[2] = (__bf16)v2; h4[3] = (__bf16)v3;
            *(bf16x4*)(sC + r16 * 256 + (colbase + kg * 4) * 2) = h4;
        } else {
            *(f32x4*)(sC + r16 * 512 + (colbase + kg * 4) * 4) =
                (f32x4){v0, v1, v2, v3};
        }
        __syncthreads();

        if (mode == 0) {
            if (tid < 256) {
                int rr = tid >> 4, c16 = tid & 15;
                int grow = t * 16 + rr;
                if (grow < n) {
                    int4 h = *(const int4*)(sC + rr * 256 + c16 * 16);
                    *(int4*)(oB + (size_t)grow * D + c16 * 8) = h;
                }
            }
        } else {
            int rr = tid >> 5, c = tid & 31;
            int grow = t * 16 + rr;
            if (grow < n) {
                f32x4 f = *(const f32x4*)(sC + rr * 512 + c * 16);
                *(f32x4*)(oF + (size_t)grow * D + c * 4) = f;
            }
        }
        cur ^= 1;
    }
}

// ---------------------------------------------------------------------------
extern "C" void kernel_launch(void* const* d_in, const int* in_sizes, int n_in,
                              void* d_out, int out_size, void* d_ws, size_t ws_size,
                              hipStream_t stream) {
    const float* x  = (const float*)d_in[0];
    const void*  ei = d_in[1];
    const float* Wa = (const float*)d_in[2];   // [3,128,128]
    const float* Wr = (const float*)d_in[3];   // [3,128,128]
    const float* bb = (const float*)d_in[4];   // [3,128]
    float* outp = (float*)d_out;

    int n  = in_sizes[0] / D;          // 100000
    int nE = in_sizes[1] / 2;          // 1600000
    int G  = (n + 511) >> 9;           // 512-node buckets (<=256)

    char* ws = (char*)d_ws;
    size_t off = 0;
    auto alloc = [&](size_t bytes) -> char* {
        char* p = ws + off;
        off = (off + bytes + 255) & ~(size_t)255;
        return p;
    };
    int* flag            = (int*)alloc(4);
    unsigned int* eword  = (unsigned int*)alloc((size_t)nE * 4);
    unsigned char* gbuf  = (unsigned char*)alloc((size_t)nE);
    unsigned int* ebuf   = (unsigned int*)alloc((size_t)nE * 4);
    int* offsets         = (int*)alloc(((size_t)n + 1) * 4);
    int* csr_src         = (int*)alloc((size_t)nE * 4);
    int* bcnt            = (int*)alloc(1024);
    int* bstart          = (int*)alloc(1024);
    int* bcur            = (int*)alloc(1024);
    __bf16* actA         = (__bf16*)alloc((size_t)n * D * 2);
    __bf16* actB         = (__bf16*)alloc((size_t)n * D * 2);
    __bf16* meanP        = (__bf16*)alloc((size_t)n * D * 2);
    __bf16* WtHi         = (__bf16*)alloc((size_t)3 * 128 * 256 * 2);
    __bf16* WtLo         = (__bf16*)alloc((size_t)3 * 128 * 256 * 2);
    (void)ws_size; (void)n_in; (void)out_size;

    const int B = 256;

    // 1) probe + fused convert/pack/hist + W transpose/split + x convert
    hipLaunchKernelGGL(detect_idx, dim3(1), dim3(64), 0, stream, ei, flag, n);
    hipMemsetAsync(bcnt, 0, 1024, stream);
    hipLaunchKernelGGL(convert_pack, dim3(512), dim3(B), 0, stream,
                       ei, flag, eword, gbuf, bcnt, nE);
    hipLaunchKernelGGL(build_wt, dim3(384), dim3(256), 0, stream, Wa, Wr, WtHi, WtLo);
    int total8 = n * D / 8;
    hipLaunchKernelGGL(cvt_x, dim3((total8 + 255) / 256), dim3(256), 0, stream,
                       x, actA, total8);

    // 2) bucketed CSR build (packed words)
    hipLaunchKernelGGL(bucket_scan, dim3(1), dim3(B), 0, stream,
                       bcnt, bstart, bcur, G, nE, offsets, n);
    hipLaunchKernelGGL(bucket_fill2, dim3((nE + CHUNK - 1) / CHUNK), dim3(B), 0, stream,
                       eword, gbuf, bcur, ebuf, nE);
    hipLaunchKernelGGL(bucket_scatter2, dim3(G), dim3(B), 0, stream,
                       ebuf, bstart, bcnt, offsets, csr_src, n);

    // 3) layers (ping-pong actA <-> actB; mean buffer reused)
    int agg_blocks = (n * 16 + B - 1) / B;
    int ntiles = (n + 15) / 16;
    int gemm_grid = 1024;              // 4 blocks/CU at 512 threads
    const int WSTRIDE = 128 * 256;

    // layer 0: actA -> actB (ReLU, bf16)
    hipLaunchKernelGGL(agg_mean5, dim3(agg_blocks), dim3(B), 0, stream,
                       actA, csr_src, offsets, meanP, n);
    hipLaunchKernelGGL(sage_gemm7, dim3(gemm_grid), dim3(512), 0, stream,
                       meanP, actA, WtHi + 0 * WSTRIDE, WtLo + 0 * WSTRIDE,
                       bb + 0 * D, actB, outp, n, 0, ntiles);

    // layer 1: actB -> actA (ReLU, bf16)
    hipLaunchKernelGGL(agg_mean5, dim3(agg_blocks), dim3(B), 0, stream,
                       actB, csr_src, offsets, meanP, n);
    hipLaunchKernelGGL(sage_gemm7, dim3(gemm_grid), dim3(512), 0, stream,
                       meanP, actB, WtHi + 1 * WSTRIDE, WtLo + 1 * WSTRIDE,
                       bb + 1 * D, actA, outp, n, 0, ntiles);

    // layer 2: actA -> d_out (no ReLU, fp32)
    hipLaunchKernelGGL(agg_mean5, dim3(agg_blocks), dim3(B), 0, stream,
                       actA, csr_src, offsets, meanP, n);
    hipLaunchKernelGGL(sage_gemm7, dim3(gemm_grid), dim3(512), 0, stream,
                       meanP, actA, WtHi + 2 * WSTRIDE, WtLo + 2 * WSTRIDE,
                       bb + 2 * D, actB, outp, n, 1, ntiles);
}

// Round 12
// 329.383 us; speedup vs baseline: 1.4166x; 1.0440x over previous
//
#include <hip/hip_runtime.h>
#include <stdint.h>

#define D 128
#define CHUNK 6400

typedef __attribute__((ext_vector_type(8))) __bf16 bf16x8;
typedef __attribute__((ext_vector_type(4))) __bf16 bf16x4;
typedef __attribute__((ext_vector_type(4))) float f32x4;

// ---------------------------------------------------------------------------
// edge_index dtype detection (int64 per reference vs int32 from x64-disabled JAX)
__global__ void detect_idx(const void* ei, int* flag, int n_nodes) {
    if (blockIdx.x == 0 && threadIdx.x == 0) {
        const long long* p = (const long long*)ei;
        int is64 = 1;
        for (int i = 0; i < 64; ++i) {
            long long v = p[i];
            if (v < 0 || v >= (long long)n_nodes) { is64 = 0; break; }
        }
        *flag = is64;
    }
}

// ---------------------------------------------------------------------------
// one pass over edge_index: packed edge word (src<<9 | dst&511), bucket byte,
// bucket histogram (LDS -> global).
__global__ __launch_bounds__(256) void convert_pack(
        const void* __restrict__ ei, const int* __restrict__ flag,
        unsigned int* __restrict__ eword, unsigned char* __restrict__ gb,
        int* __restrict__ bcnt, int nE) {
    __shared__ int l[256];
    l[threadIdx.x] = 0;
    __syncthreads();
    bool is64 = *flag != 0;
    int stride = gridDim.x * 256;
    for (int e = blockIdx.x * 256 + threadIdx.x; e < nE; e += stride) {
        int s, d;
        if (is64) {
            const long long* p = (const long long*)ei;
            s = (int)p[e];
            d = (int)p[(size_t)nE + e];
        } else {
            const int* p = (const int*)ei;
            s = p[e];
            d = p[nE + e];
        }
        eword[e] = ((unsigned)s << 9) | (unsigned)(d & 511);
        gb[e] = (unsigned char)(d >> 9);
        atomicAdd(&l[d >> 9], 1);
    }
    __syncthreads();
    int v = l[threadIdx.x];
    if (v) atomicAdd(&bcnt[threadIdx.x], v);
}

__global__ void bucket_scan(const int* __restrict__ bcnt, int* __restrict__ bstart,
                            int* __restrict__ bcur, int G, int nE,
                            int* __restrict__ offsets, int n) {
    __shared__ int s[256];
    int t = threadIdx.x;
    int v = (t < G) ? bcnt[t] : 0;
    s[t] = v;
    __syncthreads();
    for (int off = 1; off < 256; off <<= 1) {
        int u = 0;
        if (t >= off) u = s[t - off];
        __syncthreads();
        if (t >= off) s[t] += u;
        __syncthreads();
    }
    if (t < G) { int ex = s[t] - v; bstart[t] = ex; bcur[t] = ex; }
    if (t == 0) offsets[n] = nE;
}

__global__ __launch_bounds__(256) void bucket_fill2(
        const unsigned int* __restrict__ eword, const unsigned char* __restrict__ gb,
        int* __restrict__ bcur, unsigned int* __restrict__ ebuf, int nE) {
    __shared__ unsigned int lw[CHUNK];
    __shared__ unsigned char lg[CHUNK];
    __shared__ int lcnt[256], lbase[256], lcur[256];
    int e0 = blockIdx.x * CHUNK;
    int cnt = nE - e0;
    if (cnt > CHUNK) cnt = CHUNK;
    if (cnt < 0) cnt = 0;
    for (int i = threadIdx.x; i < cnt; i += 256) {
        lw[i] = eword[e0 + i];
        lg[i] = gb[e0 + i];
    }
    lcnt[threadIdx.x] = 0;
    __syncthreads();
    for (int i = threadIdx.x; i < cnt; i += 256)
        atomicAdd(&lcnt[lg[i]], 1);
    __syncthreads();
    int c = lcnt[threadIdx.x];
    if (c > 0) lbase[threadIdx.x] = atomicAdd(&bcur[threadIdx.x], c);
    lcur[threadIdx.x] = 0;
    __syncthreads();
    for (int i = threadIdx.x; i < cnt; i += 256) {
        int g = lg[i];
        int p = lbase[g] + atomicAdd(&lcur[g], 1);
        ebuf[p] = lw[i];
    }
}

__global__ __launch_bounds__(256) void bucket_scatter2(
        const unsigned int* __restrict__ ebuf,
        const int* __restrict__ bstart, const int* __restrict__ bcnt,
        int* __restrict__ offsets, int* __restrict__ csr, int n) {
    __shared__ int ncnt[512], nofs[512], ps[256];
    int g = blockIdx.x;
    int base = bstart[g];
    int cnt = bcnt[g];
    int n0 = g << 9;
    int nr = n - n0; if (nr > 512) nr = 512;
    for (int i = threadIdx.x; i < 512; i += 256) ncnt[i] = 0;
    __syncthreads();
    for (int i = threadIdx.x; i < cnt; i += 256)
        atomicAdd(&ncnt[ebuf[base + i] & 511], 1);
    __syncthreads();
    int t = threadIdx.x;
    int c0 = ncnt[2 * t], c1 = ncnt[2 * t + 1];
    ps[t] = c0 + c1;
    __syncthreads();
    for (int off = 1; off < 256; off <<= 1) {
        int u = 0;
        if (t >= off) u = ps[t - off];
        __syncthreads();
        if (t >= off) ps[t] += u;
        __syncthreads();
    }
    int pex = ps[t] - (c0 + c1);
    nofs[2 * t] = pex;
    nofs[2 * t + 1] = pex + c0;
    __syncthreads();
    for (int i = threadIdx.x; i < nr; i += 256)
        offsets[n0 + i] = base + nofs[i];
    for (int i = threadIdx.x; i < 512; i += 256) ncnt[i] = 0;   // reuse as cursor
    __syncthreads();
    for (int i = threadIdx.x; i < cnt; i += 256) {
        unsigned int w = ebuf[base + i];
        int d = w & 511;
        int p = base + nofs[d] + atomicAdd(&ncnt[d], 1);
        csr[p] = (int)(w >> 9);
    }
}

// ---------------------------------------------------------------------------
// W preprocessing: stacked [Wl;Wr] transposed to [col][k], split bf16 hi/lo.
__global__ void build_wt(const float* __restrict__ Wa, const float* __restrict__ Wr,
                         __bf16* __restrict__ WtHi, __bf16* __restrict__ WtLo) {
    int idx = blockIdx.x * 256 + threadIdx.x;         // 3*128*256 total
    if (idx >= 3 * 128 * 256) return;
    int L = idx / (128 * 256);
    int rem = idx % (128 * 256);
    int c = rem / 256;
    int k = rem % 256;
    float v = (k < 128) ? Wa[((size_t)L * 128 + k) * 128 + c]
                        : Wr[((size_t)L * 128 + (k - 128)) * 128 + c];
    __bf16 h = (__bf16)v;
    __bf16 l = (__bf16)(v - (float)h);
    WtHi[idx] = h;
    WtLo[idx] = l;
}

// ---------------------------------------------------------------------------
// x fp32 -> bf16 single plane (once, layer-0 input)
__global__ void cvt_x(const float* __restrict__ x, __bf16* __restrict__ a,
                      int total8) {
    int i = blockIdx.x * 256 + threadIdx.x;           // 8 floats per thread
    if (i >= total8) return;
    const float4* p = (const float4*)(x + (size_t)i * 8);
    float4 v0 = p[0], v1 = p[1];
    float vv[8] = {v0.x, v0.y, v0.z, v0.w, v1.x, v1.y, v1.z, v1.w};
    bf16x8 h;
    #pragma unroll
    for (int j = 0; j < 8; ++j) h[j] = (__bf16)vv[j];
    *(bf16x8*)(a + (size_t)i * 8) = h;
}

// ---------------------------------------------------------------------------
// mean aggregation (R8/R9-proven, byte-BW-bound at ~3 TB/s fetch — unchanged)
__global__ __launch_bounds__(256) void agg_mean5(
        const __bf16* __restrict__ act, const int* __restrict__ csr,
        const int* __restrict__ offs, __bf16* __restrict__ mean, int n) {
    int node = (blockIdx.x * blockDim.x + threadIdx.x) >> 4;
    int l8 = (threadIdx.x & 15) << 3;
    if (node >= n) return;
    int beg = offs[node], end = offs[node + 1];
    float acc[8] = {0.f, 0.f, 0.f, 0.f, 0.f, 0.f, 0.f, 0.f};
    int i = beg;
    for (; i + 8 <= end; i += 8) {
        bf16x8 v[8];
        #pragma unroll
        for (int u = 0; u < 8; ++u)
            v[u] = *(const bf16x8*)(act + (size_t)csr[i + u] * D + l8);
        #pragma unroll
        for (int u = 0; u < 8; ++u)
            #pragma unroll
            for (int j = 0; j < 8; ++j) acc[j] += (float)v[u][j];
    }
    for (; i + 4 <= end; i += 4) {
        bf16x8 v[4];
        #pragma unroll
        for (int u = 0; u < 4; ++u)
            v[u] = *(const bf16x8*)(act + (size_t)csr[i + u] * D + l8);
        #pragma unroll
        for (int u = 0; u < 4; ++u)
            #pragma unroll
            for (int j = 0; j < 8; ++j) acc[j] += (float)v[u][j];
    }
    for (; i < end; ++i) {
        bf16x8 v = *(const bf16x8*)(act + (size_t)csr[i] * D + l8);
        #pragma unroll
        for (int j = 0; j < 8; ++j) acc[j] += (float)v[j];
    }
    int deg = end - beg;
    float inv = 1.0f / (float)(deg > 1 ? deg : 1);
    bf16x8 h;
    #pragma unroll
    for (int j = 0; j < 8; ++j) h[j] = (__bf16)(acc[j] * inv);
    *(bf16x8*)(mean + (size_t)node * D + l8) = h;
}

// ---------------------------------------------------------------------------
// MFMA GEMM v8: like the proven gemm7 (swizzled LDS A-tile, W frags in VGPR,
// mfma(W,A) mapping, sC-transpose epilogue) but processes a 32-row PAIR of
// tiles per iteration with FOUR independent MFMA accumulator chains
// (accH/accL x half0/half1) -> MFMA latency hidden, barriers amortized 2x.
// LDS: sA 2buf x 2half x 8KB + sC 2 x 8KB = 48KB -> 2 blocks/CU.
__global__ __launch_bounds__(512, 4) void sage_gemm8(
        const __bf16* __restrict__ mean, const __bf16* __restrict__ act,
        const __bf16* __restrict__ WtHi, const __bf16* __restrict__ WtLo,
        const float* __restrict__ bias,
        __bf16* __restrict__ oB, float* __restrict__ oF,
        int n, int mode, int npairs) {
    __shared__ __align__(16) char sA[2][2][8192];  // [buf][half][row:512B, swz]
    __shared__ __align__(16) char sC[2][8192];     // [half] epilogue tile
    int tid  = threadIdx.x;
    int wave = tid >> 6;
    int lane = tid & 63;
    int r16  = lane & 15;
    int kg   = lane >> 4;
    int colbase = wave * 16;

    bf16x8 BH[8], BL[8];
    #pragma unroll
    for (int c8 = 0; c8 < 8; ++c8) {
        size_t o = (size_t)(colbase + r16) * 256 + c8 * 32 + kg * 8;
        BH[c8] = *(const bf16x8*)(WtHi + o);
        BL[c8] = *(const bf16x8*)(WtLo + o);
    }
    float4 bv = *(const float4*)(bias + colbase + kg * 4);

    int xm = (r16 & 7) << 4;
    int kb[8];
    #pragma unroll
    for (int c8 = 0; c8 < 8; ++c8)
        kb[c8] = r16 * 512 + ((c8 * 64 + kg * 16) ^ xm);

    int srow = tid >> 5;           // 0..15
    int sc16 = tid & 31;           // 0..31 (32 x 16B per row)
    int sdst = srow * 512 + ((sc16 * 16) ^ ((srow & 7) << 4));

    auto stage_load = [&](int p, int half, int4& r) {
        int grow = p * 32 + half * 16 + srow;
        if (grow < n) {
            const __bf16* src = (sc16 < 16)
                ? (mean + (size_t)grow * D + sc16 * 8)
                : (act  + (size_t)grow * D + (sc16 - 16) * 8);
            r = *(const int4*)src;
        } else {
            r = make_int4(0, 0, 0, 0);
        }
    };

    int pstride = gridDim.x;
    int p = blockIdx.x;

    {
        int4 r0 = make_int4(0,0,0,0), r1 = make_int4(0,0,0,0);
        if (p < npairs) { stage_load(p, 0, r0); stage_load(p, 1, r1); }
        *(int4*)(sA[0][0] + sdst) = r0;
        *(int4*)(sA[0][1] + sdst) = r1;
    }
    __syncthreads();
    int cur = 0;

    for (; p < npairs; p += pstride) {
        int pn = p + pstride;
        bool hasnext = pn < npairs;
        int4 n0, n1;
        if (hasnext) { stage_load(pn, 0, n0); stage_load(pn, 1, n1); }

        // 4 independent MFMA chains over 8 K-chunks
        f32x4 aH0 = (f32x4){0.f,0.f,0.f,0.f}, aL0 = aH0;
        f32x4 aH1 = aH0, aL1 = aH0;
        const char* b0 = sA[cur][0];
        const char* b1 = sA[cur][1];
        #pragma unroll
        for (int c8 = 0; c8 < 8; ++c8) {
            bf16x8 a0 = *(const bf16x8*)(b0 + kb[c8]);
            bf16x8 a1 = *(const bf16x8*)(b1 + kb[c8]);
            aH0 = __builtin_amdgcn_mfma_f32_16x16x32_bf16(BH[c8], a0, aH0, 0, 0, 0);
            aH1 = __builtin_amdgcn_mfma_f32_16x16x32_bf16(BH[c8], a1, aH1, 0, 0, 0);
            aL0 = __builtin_amdgcn_mfma_f32_16x16x32_bf16(BL[c8], a0, aL0, 0, 0, 0);
            aL1 = __builtin_amdgcn_mfma_f32_16x16x32_bf16(BL[c8], a1, aL1, 0, 0, 0);
        }

        __syncthreads();    // sA[cur] reads + previous sC readback done
        if (hasnext) {
            *(int4*)(sA[cur ^ 1][0] + sdst) = n0;
            *(int4*)(sA[cur ^ 1][1] + sdst) = n1;
        }

        // epilogue into sC[half]
        #pragma unroll
        for (int h = 0; h < 2; ++h) {
            f32x4 a = h ? (aH1 + aL1) : (aH0 + aL0);
            float v0 = a[0] + bv.x;
            float v1 = a[1] + bv.y;
            float v2 = a[2] + bv.z;
            float v3 = a[3] + bv.w;
            if (mode == 0) {
                v0 = fmaxf(v0, 0.f); v1 = fmaxf(v1, 0.f);
                v2 = fmaxf(v2, 0.f); v3 = fmaxf(v3, 0.f);
                bf16x4 h4;
                h4[0] = (__bf16)v0; h4[1] = (__bf16)v1;
                h4[2] = (__bf16)v2; h4[3] = (__bf16)v3;
                *(bf16x4*)(sC[h] + r16 * 256 + (colbase + kg * 4) * 2) = h4;
            } else {
                *(f32x4*)(sC[h] + r16 * 512 + (colbase + kg * 4) * 4) =
                    (f32x4){v0, v1, v2, v3};
            }
        }
        __syncthreads();

        // cooperative coalesced store of the 32x128 pair
        if (mode == 0) {
            int rr = tid >> 4, c16 = tid & 15;       // 512 chunks
            int grow = p * 32 + rr;
            if (grow < n) {
                int4 h = *(const int4*)(sC[rr >> 4] + (rr & 15) * 256 + c16 * 16);
                *(int4*)(oB + (size_t)grow * D + c16 * 8) = h;
            }
        } else {
            #pragma unroll
            for (int pass = 0; pass < 2; ++pass) {
                int chunk = pass * 512 + tid;
                int rr = chunk >> 5, c = chunk & 31;
                int grow = p * 32 + rr;
                if (grow < n) {
                    f32x4 f = *(const f32x4*)(sC[rr >> 4] + (rr & 15) * 512 + c * 16);
                    *(f32x4*)(oF + (size_t)grow * D + c * 4) = f;
                }
            }
        }
        cur ^= 1;
    }
}

// ---------------------------------------------------------------------------
extern "C" void kernel_launch(void* const* d_in, const int* in_sizes, int n_in,
                              void* d_out, int out_size, void* d_ws, size_t ws_size,
                              hipStream_t stream) {
    const float* x  = (const float*)d_in[0];
    const void*  ei = d_in[1];
    const float* Wa = (const float*)d_in[2];   // [3,128,128]
    const float* Wr = (const float*)d_in[3];   // [3,128,128]
    const float* bb = (const float*)d_in[4];   // [3,128]
    float* outp = (float*)d_out;

    int n  = in_sizes[0] / D;          // 100000
    int nE = in_sizes[1] / 2;          // 1600000
    int G  = (n + 511) >> 9;           // 512-node buckets (<=256)

    char* ws = (char*)d_ws;
    size_t off = 0;
    auto alloc = [&](size_t bytes) -> char* {
        char* p = ws + off;
        off = (off + bytes + 255) & ~(size_t)255;
        return p;
    };
    int* flag            = (int*)alloc(4);
    unsigned int* eword  = (unsigned int*)alloc((size_t)nE * 4);
    unsigned char* gbuf  = (unsigned char*)alloc((size_t)nE);
    unsigned int* ebuf   = (unsigned int*)alloc((size_t)nE * 4);
    int* offsets         = (int*)alloc(((size_t)n + 1) * 4);
    int* csr_src         = (int*)alloc((size_t)nE * 4);
    int* bcnt            = (int*)alloc(1024);
    int* bstart          = (int*)alloc(1024);
    int* bcur            = (int*)alloc(1024);
    __bf16* actA         = (__bf16*)alloc((size_t)n * D * 2);
    __bf16* actB         = (__bf16*)alloc((size_t)n * D * 2);
    __bf16* meanP        = (__bf16*)alloc((size_t)n * D * 2);
    __bf16* WtHi         = (__bf16*)alloc((size_t)3 * 128 * 256 * 2);
    __bf16* WtLo         = (__bf16*)alloc((size_t)3 * 128 * 256 * 2);
    (void)ws_size; (void)n_in; (void)out_size;

    const int B = 256;

    // 1) probe + fused convert/pack/hist + W transpose/split + x convert
    hipLaunchKernelGGL(detect_idx, dim3(1), dim3(64), 0, stream, ei, flag, n);
    hipMemsetAsync(bcnt, 0, 1024, stream);
    hipLaunchKernelGGL(convert_pack, dim3(512), dim3(B), 0, stream,
                       ei, flag, eword, gbuf, bcnt, nE);
    hipLaunchKernelGGL(build_wt, dim3(384), dim3(256), 0, stream, Wa, Wr, WtHi, WtLo);
    int total8 = n * D / 8;
    hipLaunchKernelGGL(cvt_x, dim3((total8 + 255) / 256), dim3(256), 0, stream,
                       x, actA, total8);

    // 2) bucketed CSR build (packed words)
    hipLaunchKernelGGL(bucket_scan, dim3(1), dim3(B), 0, stream,
                       bcnt, bstart, bcur, G, nE, offsets, n);
    hipLaunchKernelGGL(bucket_fill2, dim3((nE + CHUNK - 1) / CHUNK), dim3(B), 0, stream,
                       eword, gbuf, bcur, ebuf, nE);
    hipLaunchKernelGGL(bucket_scatter2, dim3(G), dim3(B), 0, stream,
                       ebuf, bstart, bcnt, offsets, csr_src, n);

    // 3) layers (ping-pong actA <-> actB; mean buffer reused)
    int agg_blocks = (n * 16 + B - 1) / B;
    int npairs = (n + 31) / 32;
    int gemm_grid = 512;               // 2 blocks/CU at 512 threads, 48KB LDS
    const int WSTRIDE = 128 * 256;

    // layer 0: actA -> actB (ReLU, bf16)
    hipLaunchKernelGGL(agg_mean5, dim3(agg_blocks), dim3(B), 0, stream,
                       actA, csr_src, offsets, meanP, n);
    hipLaunchKernelGGL(sage_gemm8, dim3(gemm_grid), dim3(512), 0, stream,
                       meanP, actA, WtHi + 0 * WSTRIDE, WtLo + 0 * WSTRIDE,
                       bb + 0 * D, actB, outp, n, 0, npairs);

    // layer 1: actB -> actA (ReLU, bf16)
    hipLaunchKernelGGL(agg_mean5, dim3(agg_blocks), dim3(B), 0, stream,
                       actB, csr_src, offsets, meanP, n);
    hipLaunchKernelGGL(sage_gemm8, dim3(gemm_grid), dim3(512), 0, stream,
                       meanP, actB, WtHi + 1 * WSTRIDE, WtLo + 1 * WSTRIDE,
                       bb + 1 * D, actA, outp, n, 0, npairs);

    // layer 2: actA -> d_out (no ReLU, fp32)
    hipLaunchKernelGGL(agg_mean5, dim3(agg_blocks), dim3(B), 0, stream,
                       actA, csr_src, offsets, meanP, n);
    hipLaunchKernelGGL(sage_gemm8, dim3(gemm_grid), dim3(512), 0, stream,
                       meanP, actA, WtHi + 2 * WSTRIDE, WtLo + 2 * WSTRIDE,
                       bb + 2 * D, actB, outp, n, 1, npairs);
}